// Round 1
// baseline (610.850 us; speedup 1.0000x reference)
//
#include <hip/hip_runtime.h>

#define DI __device__ __forceinline__

// ---------------- ws layout (float offsets) ----------------
// umax[8] (uint32) at 0
constexpr int OFF_WSF0 = 8;
constexpr int OFF_BNS0 = OFF_WSF0 + 32;     // 40
constexpr int OFF_BNB0 = OFF_BNS0 + 32;     // 72
constexpr int OFF_W0I  = OFF_BNB0 + 32;     // 104   (32*27 = 864)
constexpr int OFF_WSF1 = OFF_W0I  + 864;    // 968
constexpr int OFF_BNS1 = OFF_WSF1 + 4;
constexpr int OFF_BNB1 = OFF_BNS1 + 4;
constexpr int OFF_W1I  = OFF_BNB1 + 4;      // 980   (4*32 = 128)
constexpr int OFF_WSF2 = OFF_W1I  + 128;    // 1108
constexpr int OFF_BNS2 = OFF_WSF2 + 32;
constexpr int OFF_BNB2 = OFF_BNS2 + 32;
constexpr int OFF_W2I  = OFF_BNB2 + 32;     // 1204  (32*36 = 1152)
constexpr int OFF_WSF3 = OFF_W2I  + 1152;   // 2356
constexpr int OFF_BNS3 = OFF_WSF3 + 32;
constexpr int OFF_BNB3 = OFF_BNS3 + 32;
constexpr int OFF_W3I  = OFF_BNB3 + 32;     // 2452  (32*288 = 9216)
constexpr int OFF_WSF4 = OFF_W3I  + 9216;   // 11668
constexpr int OFF_BNS4 = OFF_WSF4 + 32;
constexpr int OFF_BNB4 = OFF_BNS4 + 32;
constexpr int OFF_W4I  = OFF_BNB4 + 32;     // 11764 (9216)
constexpr int OFF_WSFD = OFF_W4I  + 9216;   // 20980 (10)
constexpr int OFF_WDI  = OFF_WSFD + 10;     // 20990 (10*2048 = 20480)
constexpr int OFF_LOG  = OFF_WDI  + 20480;  // 41470 (1024*10)
constexpr int OFF_ACT  = ((OFF_LOG + 10240 + 63) / 64) * 64; // 51712
constexpr long ACT_A_OFF = OFF_ACT;                      // 33,554,432 floats (act0/act2/act4)
constexpr long ACT_B_OFF = OFF_ACT + 33554432L;          //  4,194,304 floats (act1/act3)
// peak ws use ~151.2 MB

// ---------------- helpers ----------------
DI float quantv(float x, float sf) {
    float q = rintf(x / sf);                 // matches jnp.round (half-to-even) on x/sf
    return fminf(fmaxf(q, -127.0f), 127.0f);
}
DI float get_sf(const unsigned* umax, int slot) {
    return fmaxf(__uint_as_float(umax[slot]) / 127.0f, 1e-8f);
}
DI void wave_max_atomic(float v, unsigned* dst) {
    #pragma unroll
    for (int o = 32; o; o >>= 1) v = fmaxf(v, __shfl_down(v, o, 64));
    if ((threadIdx.x & 63) == 0) atomicMax(dst, __float_as_uint(v));
}

// ---------------- kernels ----------------
__global__ void k_init(unsigned* umax) {
    if (threadIdx.x < 8) umax[threadIdx.x] = 0u;
}

__global__ __launch_bounds__(256) void k_absmax(const float4* __restrict__ x, int n4, unsigned* dst) {
    float m = 0.f;
    for (int i = blockIdx.x * blockDim.x + threadIdx.x; i < n4; i += gridDim.x * blockDim.x) {
        float4 t = x[i];
        m = fmaxf(m, fmaxf(fmaxf(fabsf(t.x), fabsf(t.y)), fmaxf(fabsf(t.z), fabsf(t.w))));
    }
    wave_max_atomic(m, dst);
}

// per-output-channel weight quant + BN fold. grid = COUT, block = 256
template<bool HAS_BN>
__global__ __launch_bounds__(256) void k_prep(const float* __restrict__ w, int K,
                                              const float* __restrict__ g, const float* __restrict__ bb,
                                              const float* __restrict__ m, const float* __restrict__ v,
                                              float* __restrict__ wsf, float* __restrict__ wint,
                                              float* __restrict__ bns, float* __restrict__ bnb) {
    int oc = blockIdx.x;
    const float* wr = w + (long)oc * K;
    float mx = 0.f;
    for (int i = threadIdx.x; i < K; i += 256) mx = fmaxf(mx, fabsf(wr[i]));
    __shared__ float red[4];
    __shared__ float s_sf;
    #pragma unroll
    for (int o = 32; o; o >>= 1) mx = fmaxf(mx, __shfl_down(mx, o, 64));
    if ((threadIdx.x & 63) == 0) red[threadIdx.x >> 6] = mx;
    __syncthreads();
    if (threadIdx.x == 0) {
        float t = fmaxf(fmaxf(red[0], red[1]), fmaxf(red[2], red[3]));
        t = fmaxf(t / 127.0f, 1e-8f);
        wsf[oc] = t; s_sf = t;
        if (HAS_BN) {
            float inv = g[oc] / sqrtf(v[oc] + 1e-5f);
            bns[oc] = inv;
            bnb[oc] = bb[oc] - m[oc] * inv;
        }
    }
    __syncthreads();
    float sf = s_sf;
    for (int i = threadIdx.x; i < K; i += 256) wint[(long)oc * K + i] = rintf(wr[i] / sf);
}

// conv0: 3->32, 3x3, s1 p1, 32x32. block = image, 256 thr = 32 rows x 8 col-quads(4 wide)
__global__ __launch_bounds__(256) void k_conv0(
    const float* __restrict__ x, const float* __restrict__ wi,
    const float* __restrict__ wsf, const float* __restrict__ bias,
    const float* __restrict__ bns, const float* __restrict__ bnb,
    const unsigned* __restrict__ umax, unsigned* __restrict__ mout,
    float* __restrict__ out) {
    int b = blockIdx.x;
    __shared__ float tile[3 * 34 * 34];
    float sf = get_sf(umax, 0);
    const float* xb = x + (long)b * 3072;
    for (int i = threadIdx.x; i < 3 * 1156; i += 256) {
        int ci = i / 1156, r = i % 1156;
        int yy = r / 34, xx = r % 34;
        int iy = yy - 1, ix = xx - 1;
        float val = 0.f;
        if ((unsigned)iy < 32u && (unsigned)ix < 32u)
            val = quantv(xb[ci * 1024 + iy * 32 + ix], sf);
        tile[i] = val;
    }
    __syncthreads();
    int t = threadIdx.x;
    int h = t >> 3;            // 0..31
    int w0 = (t & 7) * 4;      // 0..28
    float in[3][3][6];
    #pragma unroll
    for (int ci = 0; ci < 3; ++ci)
        #pragma unroll
        for (int r = 0; r < 3; ++r)
            #pragma unroll
            for (int c = 0; c < 6; ++c)
                in[ci][r][c] = tile[ci * 1156 + (h + r) * 34 + (w0 + c)];
    float lmax = 0.f;
    float* ob = out + (long)b * 32768;
    for (int oc = 0; oc < 32; ++oc) {
        float bsf = wsf[oc] * sf;
        float bint = rintf(bias[oc] / bsf);
        float bn_s = bns[oc], bn_b = bnb[oc];
        float acc[4] = {0.f, 0.f, 0.f, 0.f};
        #pragma unroll
        for (int ci = 0; ci < 3; ++ci)
            #pragma unroll
            for (int ky = 0; ky < 3; ++ky)
                #pragma unroll
                for (int kx = 0; kx < 3; ++kx) {
                    float wv = wi[oc * 27 + ci * 9 + ky * 3 + kx];
                    #pragma unroll
                    for (int dx = 0; dx < 4; ++dx)
                        acc[dx] += in[ci][ky][kx + dx] * wv;
                }
        float4 res;
        float* rp = &res.x;
        #pragma unroll
        for (int dx = 0; dx < 4; ++dx) {
            float y = (acc[dx] + bint) * bsf;
            y = y * bn_s + bn_b;
            rp[dx] = y;
            lmax = fmaxf(lmax, fabsf(y));
        }
        *(float4*)&ob[oc * 1024 + h * 32 + w0] = res;
    }
    wave_max_atomic(lmax, mout);
}

// conv1: 32->4, 1x1. thread per pixel. grid = 4096
__global__ __launch_bounds__(256) void k_conv1(
    const float* __restrict__ inp, const float* __restrict__ wi,
    const float* __restrict__ wsf, const float* __restrict__ bias,
    const float* __restrict__ bns, const float* __restrict__ bnb,
    const unsigned* __restrict__ umax, unsigned* __restrict__ mout,
    float* __restrict__ out) {
    float sf = get_sf(umax, 1);
    int gid = blockIdx.x * 256 + threadIdx.x;
    int b = gid >> 10, p = gid & 1023;
    const float* ib = inp + (long)b * 32768 + p;
    float acc[4] = {0.f, 0.f, 0.f, 0.f};
    #pragma unroll
    for (int ci = 0; ci < 32; ++ci) {
        float q = quantv(ib[ci * 1024], sf);
        #pragma unroll
        for (int oc = 0; oc < 4; ++oc) acc[oc] += q * wi[oc * 32 + ci];
    }
    float lmax = 0.f;
    float* ob = out + (long)b * 4096 + p;
    #pragma unroll
    for (int oc = 0; oc < 4; ++oc) {
        float bsf = wsf[oc] * sf;
        float bint = rintf(bias[oc] / bsf);
        float y = (acc[oc] + bint) * bsf;
        y = y * bns[oc] + bnb[oc];
        ob[oc * 1024] = y;
        lmax = fmaxf(lmax, fabsf(y));
    }
    wave_max_atomic(lmax, mout);
}

// conv2: 4->32, 3x3, s2 p1, 32x32 -> 16x16. block = image, thread = out pixel
__global__ __launch_bounds__(256) void k_conv2(
    const float* __restrict__ inp, const float* __restrict__ wi,
    const float* __restrict__ wsf, const float* __restrict__ bias,
    const float* __restrict__ bns, const float* __restrict__ bnb,
    const unsigned* __restrict__ umax, unsigned* __restrict__ mout,
    float* __restrict__ out) {
    int b = blockIdx.x;
    __shared__ float tile[4 * 34 * 34];
    float sf = get_sf(umax, 2);
    const float* ib = inp + (long)b * 4096;
    for (int i = threadIdx.x; i < 4 * 1156; i += 256) {
        int ci = i / 1156, r = i % 1156;
        int yy = r / 34, xx = r % 34;
        int iy = yy - 1, ix = xx - 1;
        float val = 0.f;
        if ((unsigned)iy < 32u && (unsigned)ix < 32u)
            val = quantv(ib[ci * 1024 + iy * 32 + ix], sf);
        tile[i] = val;
    }
    __syncthreads();
    int t = threadIdx.x;
    int h = t >> 4, w = t & 15;
    float in[4][9];
    #pragma unroll
    for (int ci = 0; ci < 4; ++ci)
        #pragma unroll
        for (int ky = 0; ky < 3; ++ky)
            #pragma unroll
            for (int kx = 0; kx < 3; ++kx)
                in[ci][ky * 3 + kx] = tile[ci * 1156 + (2 * h + ky) * 34 + (2 * w + kx)];
    float lmax = 0.f;
    float* ob = out + (long)b * 8192;
    for (int oc = 0; oc < 32; ++oc) {
        float acc = 0.f;
        #pragma unroll
        for (int ci = 0; ci < 4; ++ci)
            #pragma unroll
            for (int j = 0; j < 9; ++j)
                acc += in[ci][j] * wi[oc * 36 + ci * 9 + j];
        float bsf = wsf[oc] * sf;
        float bint = rintf(bias[oc] / bsf);
        float y = (acc + bint) * bsf;
        y = y * bns[oc] + bnb[oc];
        ob[oc * 256 + t] = y;
        lmax = fmaxf(lmax, fabsf(y));
    }
    wave_max_atomic(lmax, mout);
}

// conv3/conv4: 32->32, 3x3, pad 1, out 8x8. block = image; thread = (pix 0..63, ocg 0..3)
template<int HIN, int S>
__global__ __launch_bounds__(256) void k_conv34(
    const float* __restrict__ inp, const float* __restrict__ wi,
    const float* __restrict__ wsf, const float* __restrict__ bias,
    const float* __restrict__ bns, const float* __restrict__ bnb,
    const unsigned* __restrict__ umax, int slot, unsigned* __restrict__ mout,
    float* __restrict__ out) {
    constexpr int HP = HIN + 2;
    constexpr int PP = HP * HP;
    constexpr int IN_N = 32 * PP;
    int b = blockIdx.x;
    __shared__ float tile[IN_N];
    float sf = get_sf(umax, slot);
    const float* ib = inp + (long)b * 32 * HIN * HIN;
    for (int i = threadIdx.x; i < IN_N; i += 256) {
        int ci = i / PP, r = i % PP;
        int yy = r / HP, xx = r % HP;
        int iy = yy - 1, ix = xx - 1;
        float val = 0.f;
        if ((unsigned)iy < (unsigned)HIN && (unsigned)ix < (unsigned)HIN)
            val = quantv(ib[ci * HIN * HIN + iy * HIN + ix], sf);
        tile[i] = val;
    }
    __syncthreads();
    int pix = threadIdx.x & 63;
    int ocg = __builtin_amdgcn_readfirstlane(threadIdx.x >> 6);
    int h = pix >> 3, w = pix & 7;
    float acc[8] = {0.f, 0.f, 0.f, 0.f, 0.f, 0.f, 0.f, 0.f};
    for (int ci = 0; ci < 32; ++ci) {
        float tv[9];
        #pragma unroll
        for (int ky = 0; ky < 3; ++ky)
            #pragma unroll
            for (int kx = 0; kx < 3; ++kx)
                tv[ky * 3 + kx] = tile[ci * PP + (S * h + ky) * HP + (S * w + kx)];
        #pragma unroll
        for (int k = 0; k < 8; ++k) {
            int oc = ocg * 8 + k;
            #pragma unroll
            for (int j = 0; j < 9; ++j)
                acc[k] += tv[j] * wi[oc * 288 + ci * 9 + j];
        }
    }
    float lmax = 0.f;
    float* ob = out + (long)b * 2048;
    #pragma unroll
    for (int k = 0; k < 8; ++k) {
        int oc = ocg * 8 + k;
        float bsf = wsf[oc] * sf;
        float bint = rintf(bias[oc] / bsf);
        float y = (acc[k] + bint) * bsf;
        y = y * bns[oc] + bnb[oc];
        ob[oc * 64 + pix] = y;
        lmax = fmaxf(lmax, fabsf(y));
    }
    wave_max_atomic(lmax, mout);
}

// linear 2048->10 per image + write logits
__global__ __launch_bounds__(256) void k_fc(
    const float* __restrict__ act, const float* __restrict__ wdi,
    const float* __restrict__ wsfd, const float* __restrict__ bd,
    const unsigned* __restrict__ umax, float* __restrict__ logits) {
    int b = blockIdx.x;
    float sf = get_sf(umax, 5);
    const float* ab = act + (long)b * 2048;
    float acc[10] = {0.f, 0.f, 0.f, 0.f, 0.f, 0.f, 0.f, 0.f, 0.f, 0.f};
    #pragma unroll
    for (int k = 0; k < 8; ++k) {
        int j = threadIdx.x + 256 * k;
        float q = quantv(ab[j], sf);
        #pragma unroll
        for (int c = 0; c < 10; ++c) acc[c] += q * wdi[c * 2048 + j];
    }
    #pragma unroll
    for (int c = 0; c < 10; ++c)
        #pragma unroll
        for (int o = 32; o; o >>= 1) acc[c] += __shfl_down(acc[c], o, 64);
    __shared__ float red[4][10];
    int wid = threadIdx.x >> 6;
    if ((threadIdx.x & 63) == 0)
        #pragma unroll
        for (int c = 0; c < 10; ++c) red[wid][c] = acc[c];
    __syncthreads();
    if (threadIdx.x < 10) {
        int c = threadIdx.x;
        float s = red[0][c] + red[1][c] + red[2][c] + red[3][c];
        float bsf = wsfd[c] * sf;
        float bint = rintf(bd[c] / bsf);
        logits[b * 10 + c] = (s + bint) * bsf;
    }
}

// softmax over batch axis (dim 0). one block per class column
__global__ __launch_bounds__(256) void k_softmax(const float* __restrict__ logits, float* __restrict__ out) {
    int c = blockIdx.x;
    float v[4];
    #pragma unroll
    for (int k = 0; k < 4; ++k) v[k] = logits[(threadIdx.x + 256 * k) * 10 + c];
    float mx = fmaxf(fmaxf(v[0], v[1]), fmaxf(v[2], v[3]));
    __shared__ float redm[4];
    __shared__ float reds[4];
    #pragma unroll
    for (int o = 32; o; o >>= 1) mx = fmaxf(mx, __shfl_down(mx, o, 64));
    if ((threadIdx.x & 63) == 0) redm[threadIdx.x >> 6] = mx;
    __syncthreads();
    mx = fmaxf(fmaxf(redm[0], redm[1]), fmaxf(redm[2], redm[3]));
    float e[4], s = 0.f;
    #pragma unroll
    for (int k = 0; k < 4; ++k) { e[k] = expf(v[k] - mx); s += e[k]; }
    #pragma unroll
    for (int o = 32; o; o >>= 1) s += __shfl_down(s, o, 64);
    if ((threadIdx.x & 63) == 0) reds[threadIdx.x >> 6] = s;
    __syncthreads();
    s = reds[0] + reds[1] + reds[2] + reds[3];
    #pragma unroll
    for (int k = 0; k < 4; ++k) out[(threadIdx.x + 256 * k) * 10 + c] = e[k] / s;
}

extern "C" void kernel_launch(void* const* d_in, const int* in_sizes, int n_in,
                              void* d_out, int out_size, void* d_ws, size_t ws_size,
                              hipStream_t stream) {
    (void)in_sizes; (void)n_in; (void)out_size; (void)ws_size;
    const float* x = (const float*)d_in[0];
    const float *w[5], *bia[5], *g[5], *bb[5], *m[5], *v[5];
    for (int i = 0; i < 5; ++i) {
        w[i]   = (const float*)d_in[1 + 6 * i + 0];
        bia[i] = (const float*)d_in[1 + 6 * i + 1];
        g[i]   = (const float*)d_in[1 + 6 * i + 2];
        bb[i]  = (const float*)d_in[1 + 6 * i + 3];
        m[i]   = (const float*)d_in[1 + 6 * i + 4];
        v[i]   = (const float*)d_in[1 + 6 * i + 5];
    }
    const float* wd = (const float*)d_in[31];
    const float* bd = (const float*)d_in[32];
    float* ws = (float*)d_ws;
    unsigned* umax = (unsigned*)ws;
    float* out = (float*)d_out;

    float* wsf0 = ws + OFF_WSF0; float* bns0 = ws + OFF_BNS0; float* bnb0 = ws + OFF_BNB0; float* w0i = ws + OFF_W0I;
    float* wsf1 = ws + OFF_WSF1; float* bns1 = ws + OFF_BNS1; float* bnb1 = ws + OFF_BNB1; float* w1i = ws + OFF_W1I;
    float* wsf2 = ws + OFF_WSF2; float* bns2 = ws + OFF_BNS2; float* bnb2 = ws + OFF_BNB2; float* w2i = ws + OFF_W2I;
    float* wsf3 = ws + OFF_WSF3; float* bns3 = ws + OFF_BNS3; float* bnb3 = ws + OFF_BNB3; float* w3i = ws + OFF_W3I;
    float* wsf4 = ws + OFF_WSF4; float* bns4 = ws + OFF_BNS4; float* bnb4 = ws + OFF_BNB4; float* w4i = ws + OFF_W4I;
    float* wsfd = ws + OFF_WSFD; float* wdi = ws + OFF_WDI;
    float* logits = ws + OFF_LOG;
    float* actA = ws + ACT_A_OFF;   // act0 / act2 / act4
    float* actB = ws + ACT_B_OFF;   // act1 / act3

    hipLaunchKernelGGL(k_init, dim3(1), dim3(64), 0, stream, umax);
    hipLaunchKernelGGL(k_absmax, dim3(1024), dim3(256), 0, stream,
                       (const float4*)x, 1024 * 3 * 32 * 32 / 4, umax + 0);
    hipLaunchKernelGGL((k_prep<true>),  dim3(32), dim3(256), 0, stream, w[0], 27,  g[0], bb[0], m[0], v[0], wsf0, w0i, bns0, bnb0);
    hipLaunchKernelGGL((k_prep<true>),  dim3(4),  dim3(256), 0, stream, w[1], 32,  g[1], bb[1], m[1], v[1], wsf1, w1i, bns1, bnb1);
    hipLaunchKernelGGL((k_prep<true>),  dim3(32), dim3(256), 0, stream, w[2], 36,  g[2], bb[2], m[2], v[2], wsf2, w2i, bns2, bnb2);
    hipLaunchKernelGGL((k_prep<true>),  dim3(32), dim3(256), 0, stream, w[3], 288, g[3], bb[3], m[3], v[3], wsf3, w3i, bns3, bnb3);
    hipLaunchKernelGGL((k_prep<true>),  dim3(32), dim3(256), 0, stream, w[4], 288, g[4], bb[4], m[4], v[4], wsf4, w4i, bns4, bnb4);
    hipLaunchKernelGGL((k_prep<false>), dim3(10), dim3(256), 0, stream, wd, 2048, nullptr, nullptr, nullptr, nullptr, wsfd, wdi, nullptr, nullptr);

    hipLaunchKernelGGL(k_conv0, dim3(1024), dim3(256), 0, stream, x,    w0i, wsf0, bia[0], bns0, bnb0, umax, umax + 1, actA);
    hipLaunchKernelGGL(k_conv1, dim3(4096), dim3(256), 0, stream, actA, w1i, wsf1, bia[1], bns1, bnb1, umax, umax + 2, actB);
    hipLaunchKernelGGL(k_conv2, dim3(1024), dim3(256), 0, stream, actB, w2i, wsf2, bia[2], bns2, bnb2, umax, umax + 3, actA);
    hipLaunchKernelGGL((k_conv34<16, 2>), dim3(1024), dim3(256), 0, stream, actA, w3i, wsf3, bia[3], bns3, bnb3, umax, 3, umax + 4, actB);
    hipLaunchKernelGGL((k_conv34<8, 1>),  dim3(1024), dim3(256), 0, stream, actB, w4i, wsf4, bia[4], bns4, bnb4, umax, 4, umax + 5, actA);
    hipLaunchKernelGGL(k_fc, dim3(1024), dim3(256), 0, stream, actA, wdi, wsfd, bd, umax, logits);
    hipLaunchKernelGGL(k_softmax, dim3(10), dim3(256), 0, stream, logits, out);
}

// Round 2
// 468.240 us; speedup vs baseline: 1.3046x; 1.3046x over previous
//
#include <hip/hip_runtime.h>

#define DI __device__ __forceinline__

// ---------------- ws layout (float offsets), all 4-float aligned ----------------
// umax[8] (uint32) at 0:
//   [0]=|x| [1]=|act0| [2]=|act1| [3]=|act2| [4]=|act3| [5]=|act4|
constexpr int OFF_WSF0 = 8;
constexpr int OFF_BNS0 = 40;
constexpr int OFF_BNB0 = 72;
constexpr int OFF_W0I  = 104;    // 32*27 = 864
constexpr int OFF_WSF1 = 968;
constexpr int OFF_BNS1 = 972;
constexpr int OFF_BNB1 = 976;
constexpr int OFF_W1I  = 980;    // 4*32 = 128
constexpr int OFF_WSF2 = 1108;
constexpr int OFF_BNS2 = 1140;
constexpr int OFF_BNB2 = 1172;
constexpr int OFF_W2I  = 1204;   // 32*36 = 1152
constexpr int OFF_WSF3 = 2356;
constexpr int OFF_BNS3 = 2388;
constexpr int OFF_BNB3 = 2420;
constexpr int OFF_W3I  = 2452;   // 32*288 = 9216
constexpr int OFF_WSF4 = 11668;
constexpr int OFF_BNS4 = 11700;
constexpr int OFF_BNB4 = 11732;
constexpr int OFF_W4I  = 11764;  // 9216
constexpr int OFF_WSFD = 20980;  // 10
constexpr int OFF_WDI  = 20992;  // 10*2048 = 20480
constexpr int OFF_LOG  = 41472;  // 1024*10
constexpr int OFF_ACT  = 51712;
constexpr long ACT_A_OFF = OFF_ACT;              // act2/act4 (8,388,608 floats)
constexpr long ACT_B_OFF = OFF_ACT + 8388608L;   // act1/act3 (4,194,304 floats)
// peak ws use ~50.5 MB

// ---------------- helpers ----------------
DI float quantv(float x, float sf) {
    float q = rintf(x / sf);
    return fminf(fmaxf(q, -127.0f), 127.0f);
}
DI float get_sf(const unsigned* umax, int slot) {
    return fmaxf(__uint_as_float(umax[slot]) / 127.0f, 1e-8f);
}
DI void wave_max_atomic(float v, unsigned* dst) {
    #pragma unroll
    for (int o = 32; o; o >>= 1) v = fmaxf(v, __shfl_down(v, o, 64));
    if ((threadIdx.x & 63) == 0) atomicMax(dst, __float_as_uint(v));
}

// ---------------- prep: weight quant + BN fold, all layers in one launch ----------------
struct PrepEntry {
    const float *w, *g, *bb, *m, *v;
    float *wsf, *wint, *bns, *bnb;
    int K; int has_bn;
};
struct PrepAll { PrepEntry e[6]; unsigned* umax; };

__global__ __launch_bounds__(256) void k_prep_all(PrepAll pa) {
    int blk = blockIdx.x;
    if (blk == 142) { if (threadIdx.x < 8) pa.umax[threadIdx.x] = 0u; return; }
    int layer, oc;
    if      (blk < 32)  { layer = 0; oc = blk; }
    else if (blk < 36)  { layer = 1; oc = blk - 32; }
    else if (blk < 68)  { layer = 2; oc = blk - 36; }
    else if (blk < 100) { layer = 3; oc = blk - 68; }
    else if (blk < 132) { layer = 4; oc = blk - 100; }
    else                { layer = 5; oc = blk - 132; }
    PrepEntry a = pa.e[layer];
    const float* wr = a.w + (long)oc * a.K;
    float mx = 0.f;
    for (int i = threadIdx.x; i < a.K; i += 256) mx = fmaxf(mx, fabsf(wr[i]));
    __shared__ float red[4];
    __shared__ float s_sf;
    #pragma unroll
    for (int o = 32; o; o >>= 1) mx = fmaxf(mx, __shfl_down(mx, o, 64));
    if ((threadIdx.x & 63) == 0) red[threadIdx.x >> 6] = mx;
    __syncthreads();
    if (threadIdx.x == 0) {
        float t = fmaxf(fmaxf(red[0], red[1]), fmaxf(red[2], red[3]));
        t = fmaxf(t / 127.0f, 1e-8f);
        a.wsf[oc] = t; s_sf = t;
        if (a.has_bn) {
            float inv = a.g[oc] / sqrtf(a.v[oc] + 1e-5f);
            a.bns[oc] = inv;
            a.bnb[oc] = a.bb[oc] - a.m[oc] * inv;
        }
    }
    __syncthreads();
    float sf = s_sf;
    for (int i = threadIdx.x; i < a.K; i += 256) a.wint[(long)oc * a.K + i] = rintf(wr[i] / sf);
}

__global__ __launch_bounds__(256) void k_absmax(const float4* __restrict__ x, int n4, unsigned* dst) {
    float m = 0.f;
    for (int i = blockIdx.x * blockDim.x + threadIdx.x; i < n4; i += gridDim.x * blockDim.x) {
        float4 t = x[i];
        m = fmaxf(m, fmaxf(fmaxf(fabsf(t.x), fabsf(t.y)), fmaxf(fabsf(t.z), fabsf(t.w))));
    }
    wave_max_atomic(m, dst);
}

// ---------------- conv0 common machinery ----------------
// block = one image. 256 thr: h = t>>3 (0..31), w0 = (t&7)*4 (4-wide pixel quad).
DI void conv0_stage(const float* xb, float sfx, float* tile) {
    for (int i = threadIdx.x; i < 3 * 1156; i += 256) {
        int ci = i / 1156, r = i % 1156;
        int yy = r / 34, xx = r % 34;
        int iy = yy - 1, ix = xx - 1;
        float val = 0.f;
        if ((unsigned)iy < 32u && (unsigned)ix < 32u)
            val = quantv(xb[ci * 1024 + iy * 32 + ix], sfx);
        tile[i] = val;
    }
}
DI void conv0_inregs(const float* tile, int h, int w0, float in[3][3][6]) {
    #pragma unroll
    for (int ci = 0; ci < 3; ++ci)
        #pragma unroll
        for (int r = 0; r < 3; ++r)
            #pragma unroll
            for (int c = 0; c < 6; ++c)
                in[ci][r][c] = tile[ci * 1156 + (h + r) * 34 + (w0 + c)];
}
DI void conv0_oc(const float in[3][3][6], const float* w0s, int oc, float acc[4]) {
    acc[0] = acc[1] = acc[2] = acc[3] = 0.f;
    #pragma unroll
    for (int ci = 0; ci < 3; ++ci)
        #pragma unroll
        for (int ky = 0; ky < 3; ++ky)
            #pragma unroll
            for (int kx = 0; kx < 3; ++kx) {
                float wv = w0s[oc * 27 + ci * 9 + ky * 3 + kx];
                #pragma unroll
                for (int dx = 0; dx < 4; ++dx)
                    acc[dx] = fmaf(in[ci][ky][kx + dx], wv, acc[dx]);
            }
}

// pass 1: conv0+BN, global max of act0 only — no write
__global__ __launch_bounds__(256) void k_conv0max(
    const float* __restrict__ x, const float* __restrict__ w0i,
    const float* __restrict__ wsf0, const float* __restrict__ bias0,
    const float* __restrict__ bns0, const float* __restrict__ bnb0,
    const unsigned* __restrict__ umax, unsigned* __restrict__ mout) {
    int b = blockIdx.x;
    __shared__ float tile[3 * 1156];
    __shared__ float w0s[864];
    __shared__ float A0s[32], C0s[32];
    float sfx = get_sf(umax, 0);
    if (threadIdx.x < 32) {
        int oc = threadIdx.x;
        float bsf = wsf0[oc] * sfx;
        float bint = rintf(bias0[oc] / bsf);
        float a = bsf * bns0[oc];
        A0s[oc] = a;
        C0s[oc] = fmaf(bint, a, bnb0[oc]);
    }
    for (int i = threadIdx.x; i < 864; i += 256) w0s[i] = w0i[i];
    conv0_stage(x + (long)b * 3072, sfx, tile);
    __syncthreads();
    int t = threadIdx.x;
    int h = t >> 3, w0 = (t & 7) * 4;
    float in[3][3][6];
    conv0_inregs(tile, h, w0, in);
    float lmax = 0.f;
    for (int oc = 0; oc < 32; ++oc) {
        float acc[4];
        conv0_oc(in, w0s, oc, acc);
        float A = A0s[oc], C = C0s[oc];
        #pragma unroll
        for (int dx = 0; dx < 4; ++dx)
            lmax = fmaxf(lmax, fabsf(fmaf(acc[dx], A, C)));
    }
    wave_max_atomic(lmax, mout);
}

// pass 2: recompute conv0 (identical) + quantize act0 on the fly + fused 1x1 conv1+BN
__global__ __launch_bounds__(256) void k_conv01(
    const float* __restrict__ x, const float* __restrict__ w0i,
    const float* __restrict__ wsf0, const float* __restrict__ bias0,
    const float* __restrict__ bns0, const float* __restrict__ bnb0,
    const float* __restrict__ w1i,
    const float* __restrict__ wsf1, const float* __restrict__ bias1,
    const float* __restrict__ bns1, const float* __restrict__ bnb1,
    const unsigned* __restrict__ umax, unsigned* __restrict__ mout,
    float* __restrict__ out) {
    int b = blockIdx.x;
    __shared__ float tile[3 * 1156];
    __shared__ float w0s[864];
    __shared__ float w1s[128];
    __shared__ float A0s[32], C0s[32];
    __shared__ float A1s[4], C1s[4];
    float sfx = get_sf(umax, 0);
    float sf1 = get_sf(umax, 1);   // act0 scale
    if (threadIdx.x < 32) {
        int oc = threadIdx.x;
        float bsf = wsf0[oc] * sfx;
        float bint = rintf(bias0[oc] / bsf);
        float a = bsf * bns0[oc];
        A0s[oc] = a;
        C0s[oc] = fmaf(bint, a, bnb0[oc]);
    }
    if (threadIdx.x >= 64 && threadIdx.x < 68) {
        int oc = threadIdx.x - 64;
        float bsf = wsf1[oc] * sf1;
        float bint = rintf(bias1[oc] / bsf);
        float a = bsf * bns1[oc];
        A1s[oc] = a;
        C1s[oc] = fmaf(bint, a, bnb1[oc]);
    }
    for (int i = threadIdx.x; i < 864; i += 256) w0s[i] = w0i[i];
    if (threadIdx.x >= 128 && threadIdx.x < 256) w1s[threadIdx.x - 128] = w1i[threadIdx.x - 128];
    conv0_stage(x + (long)b * 3072, sfx, tile);
    __syncthreads();
    int t = threadIdx.x;
    int h = t >> 3, w0 = (t & 7) * 4;
    float in[3][3][6];
    conv0_inregs(tile, h, w0, in);
    float acc1[4][4] = {{0.f}};
    for (int oc = 0; oc < 32; ++oc) {
        float acc[4];
        conv0_oc(in, w0s, oc, acc);
        float A = A0s[oc], C = C0s[oc];
        float wv0 = w1s[oc], wv1 = w1s[32 + oc], wv2 = w1s[64 + oc], wv3 = w1s[96 + oc];
        #pragma unroll
        for (int dx = 0; dx < 4; ++dx) {
            float y = fmaf(acc[dx], A, C);          // act0 value (identical to k_conv0max)
            float q = quantv(y, sf1);
            acc1[0][dx] = fmaf(q, wv0, acc1[0][dx]);
            acc1[1][dx] = fmaf(q, wv1, acc1[1][dx]);
            acc1[2][dx] = fmaf(q, wv2, acc1[2][dx]);
            acc1[3][dx] = fmaf(q, wv3, acc1[3][dx]);
        }
    }
    float lmax = 0.f;
    float* ob = out + (long)b * 4096;
    #pragma unroll
    for (int o1 = 0; o1 < 4; ++o1) {
        float A = A1s[o1], C = C1s[o1];
        float4 res;
        float* rp = &res.x;
        #pragma unroll
        for (int dx = 0; dx < 4; ++dx) {
            float y = fmaf(acc1[o1][dx], A, C);
            rp[dx] = y;
            lmax = fmaxf(lmax, fabsf(y));
        }
        *(float4*)&ob[o1 * 1024 + h * 32 + w0] = res;
    }
    wave_max_atomic(lmax, mout);
}

// conv2: 4->32, 3x3, s2 p1, 32x32 -> 16x16. block = image, thread = out pixel
__global__ __launch_bounds__(256) void k_conv2(
    const float* __restrict__ inp, const float* __restrict__ wi,
    const float* __restrict__ wsf, const float* __restrict__ bias,
    const float* __restrict__ bns, const float* __restrict__ bnb,
    const unsigned* __restrict__ umax, unsigned* __restrict__ mout,
    float* __restrict__ out) {
    int b = blockIdx.x;
    __shared__ float tile[4 * 1156];
    __shared__ float wls[1152];
    __shared__ float As[32], Cs[32];
    float sf = get_sf(umax, 2);
    if (threadIdx.x < 32) {
        int oc = threadIdx.x;
        float bsf = wsf[oc] * sf;
        float bint = rintf(bias[oc] / bsf);
        float a = bsf * bns[oc];
        As[oc] = a;
        Cs[oc] = fmaf(bint, a, bnb[oc]);
    }
    for (int i = threadIdx.x; i < 1152; i += 256) wls[i] = wi[i];
    const float* ib = inp + (long)b * 4096;
    for (int i = threadIdx.x; i < 4 * 1156; i += 256) {
        int ci = i / 1156, r = i % 1156;
        int yy = r / 34, xx = r % 34;
        int iy = yy - 1, ix = xx - 1;
        float val = 0.f;
        if ((unsigned)iy < 32u && (unsigned)ix < 32u)
            val = quantv(ib[ci * 1024 + iy * 32 + ix], sf);
        tile[i] = val;
    }
    __syncthreads();
    int t = threadIdx.x;
    int h = t >> 4, w = t & 15;
    float in[4][9];
    #pragma unroll
    for (int ci = 0; ci < 4; ++ci)
        #pragma unroll
        for (int ky = 0; ky < 3; ++ky)
            #pragma unroll
            for (int kx = 0; kx < 3; ++kx)
                in[ci][ky * 3 + kx] = tile[ci * 1156 + (2 * h + ky) * 34 + (2 * w + kx)];
    float lmax = 0.f;
    float* ob = out + (long)b * 8192;
    for (int oc = 0; oc < 32; ++oc) {
        float acc = 0.f;
        #pragma unroll
        for (int ci = 0; ci < 4; ++ci)
            #pragma unroll
            for (int j = 0; j < 9; ++j)
                acc = fmaf(in[ci][j], wls[oc * 36 + ci * 9 + j], acc);
        float y = fmaf(acc, As[oc], Cs[oc]);
        ob[oc * 256 + t] = y;
        lmax = fmaxf(lmax, fabsf(y));
    }
    wave_max_atomic(lmax, mout);
}

// conv3/conv4: 32->32, 3x3, pad 1, out 8x8. block = image; thread = (pix 0..63, ocg 0..3)
template<int HIN, int S>
__global__ __launch_bounds__(256) void k_conv34(
    const float* __restrict__ inp, const float* __restrict__ wi,
    const float* __restrict__ wsf, const float* __restrict__ bias,
    const float* __restrict__ bns, const float* __restrict__ bnb,
    const unsigned* __restrict__ umax, int slot, unsigned* __restrict__ mout,
    float* __restrict__ out) {
    constexpr int HP = HIN + 2;
    constexpr int PP = HP * HP;
    constexpr int IN_N = 32 * PP;
    int b = blockIdx.x;
    __shared__ float tile[IN_N];
    __shared__ float wls[9216];
    __shared__ float As[32], Cs[32];
    float sf = get_sf(umax, slot);
    if (threadIdx.x < 32) {
        int oc = threadIdx.x;
        float bsf = wsf[oc] * sf;
        float bint = rintf(bias[oc] / bsf);
        float a = bsf * bns[oc];
        As[oc] = a;
        Cs[oc] = fmaf(bint, a, bnb[oc]);
    }
    {   // vectorized weight stage: 9216 floats = 2304 float4
        const float4* w4 = (const float4*)wi;
        float4* s4 = (float4*)wls;
        for (int i = threadIdx.x; i < 2304; i += 256) s4[i] = w4[i];
    }
    const float* ib = inp + (long)b * 32 * HIN * HIN;
    for (int i = threadIdx.x; i < IN_N; i += 256) {
        int ci = i / PP, r = i % PP;
        int yy = r / HP, xx = r % HP;
        int iy = yy - 1, ix = xx - 1;
        float val = 0.f;
        if ((unsigned)iy < (unsigned)HIN && (unsigned)ix < (unsigned)HIN)
            val = quantv(ib[ci * HIN * HIN + iy * HIN + ix], sf);
        tile[i] = val;
    }
    __syncthreads();
    int pix = threadIdx.x & 63;
    int ocg = __builtin_amdgcn_readfirstlane(threadIdx.x >> 6);
    int h = pix >> 3, w = pix & 7;
    float acc[8] = {0.f, 0.f, 0.f, 0.f, 0.f, 0.f, 0.f, 0.f};
    for (int ci = 0; ci < 32; ++ci) {
        float tv[9];
        #pragma unroll
        for (int ky = 0; ky < 3; ++ky)
            #pragma unroll
            for (int kx = 0; kx < 3; ++kx)
                tv[ky * 3 + kx] = tile[ci * PP + (S * h + ky) * HP + (S * w + kx)];
        #pragma unroll
        for (int k = 0; k < 8; ++k) {
            int oc = ocg * 8 + k;
            #pragma unroll
            for (int j = 0; j < 9; ++j)
                acc[k] = fmaf(tv[j], wls[oc * 288 + ci * 9 + j], acc[k]);
        }
    }
    float lmax = 0.f;
    float* ob = out + (long)b * 2048;
    #pragma unroll
    for (int k = 0; k < 8; ++k) {
        int oc = ocg * 8 + k;
        float y = fmaf(acc[k], As[oc], Cs[oc]);
        ob[oc * 64 + pix] = y;
        lmax = fmaxf(lmax, fabsf(y));
    }
    wave_max_atomic(lmax, mout);
}

// linear 2048->10 per image
__global__ __launch_bounds__(256) void k_fc(
    const float* __restrict__ act, const float* __restrict__ wdi,
    const float* __restrict__ wsfd, const float* __restrict__ bd,
    const unsigned* __restrict__ umax, float* __restrict__ logits) {
    int b = blockIdx.x;
    float sf = get_sf(umax, 5);
    const float* ab = act + (long)b * 2048;
    float acc[10] = {0.f, 0.f, 0.f, 0.f, 0.f, 0.f, 0.f, 0.f, 0.f, 0.f};
    #pragma unroll
    for (int k = 0; k < 8; ++k) {
        int j = threadIdx.x + 256 * k;
        float q = quantv(ab[j], sf);
        #pragma unroll
        for (int c = 0; c < 10; ++c) acc[c] = fmaf(q, wdi[c * 2048 + j], acc[c]);
    }
    #pragma unroll
    for (int c = 0; c < 10; ++c)
        #pragma unroll
        for (int o = 32; o; o >>= 1) acc[c] += __shfl_down(acc[c], o, 64);
    __shared__ float red[4][10];
    int wid = threadIdx.x >> 6;
    if ((threadIdx.x & 63) == 0)
        #pragma unroll
        for (int c = 0; c < 10; ++c) red[wid][c] = acc[c];
    __syncthreads();
    if (threadIdx.x < 10) {
        int c = threadIdx.x;
        float s = red[0][c] + red[1][c] + red[2][c] + red[3][c];
        float bsf = wsfd[c] * sf;
        float bint = rintf(bd[c] / bsf);
        logits[b * 10 + c] = (s + bint) * bsf;
    }
}

// softmax over batch axis (dim 0). one block per class column
__global__ __launch_bounds__(256) void k_softmax(const float* __restrict__ logits, float* __restrict__ out) {
    int c = blockIdx.x;
    float v[4];
    #pragma unroll
    for (int k = 0; k < 4; ++k) v[k] = logits[(threadIdx.x + 256 * k) * 10 + c];
    float mx = fmaxf(fmaxf(v[0], v[1]), fmaxf(v[2], v[3]));
    __shared__ float redm[4];
    __shared__ float reds[4];
    #pragma unroll
    for (int o = 32; o; o >>= 1) mx = fmaxf(mx, __shfl_down(mx, o, 64));
    if ((threadIdx.x & 63) == 0) redm[threadIdx.x >> 6] = mx;
    __syncthreads();
    mx = fmaxf(fmaxf(redm[0], redm[1]), fmaxf(redm[2], redm[3]));
    float e[4], s = 0.f;
    #pragma unroll
    for (int k = 0; k < 4; ++k) { e[k] = expf(v[k] - mx); s += e[k]; }
    #pragma unroll
    for (int o = 32; o; o >>= 1) s += __shfl_down(s, o, 64);
    if ((threadIdx.x & 63) == 0) reds[threadIdx.x >> 6] = s;
    __syncthreads();
    s = reds[0] + reds[1] + reds[2] + reds[3];
    #pragma unroll
    for (int k = 0; k < 4; ++k) out[(threadIdx.x + 256 * k) * 10 + c] = e[k] / s;
}

extern "C" void kernel_launch(void* const* d_in, const int* in_sizes, int n_in,
                              void* d_out, int out_size, void* d_ws, size_t ws_size,
                              hipStream_t stream) {
    (void)in_sizes; (void)n_in; (void)out_size; (void)ws_size;
    const float* x = (const float*)d_in[0];
    const float *w[5], *bia[5], *g[5], *bb[5], *m[5], *v[5];
    for (int i = 0; i < 5; ++i) {
        w[i]   = (const float*)d_in[1 + 6 * i + 0];
        bia[i] = (const float*)d_in[1 + 6 * i + 1];
        g[i]   = (const float*)d_in[1 + 6 * i + 2];
        bb[i]  = (const float*)d_in[1 + 6 * i + 3];
        m[i]   = (const float*)d_in[1 + 6 * i + 4];
        v[i]   = (const float*)d_in[1 + 6 * i + 5];
    }
    const float* wd = (const float*)d_in[31];
    const float* bd = (const float*)d_in[32];
    float* ws = (float*)d_ws;
    unsigned* umax = (unsigned*)ws;
    float* out = (float*)d_out;

    float* wsf0 = ws + OFF_WSF0; float* bns0 = ws + OFF_BNS0; float* bnb0 = ws + OFF_BNB0; float* w0i = ws + OFF_W0I;
    float* wsf1 = ws + OFF_WSF1; float* bns1 = ws + OFF_BNS1; float* bnb1 = ws + OFF_BNB1; float* w1i = ws + OFF_W1I;
    float* wsf2 = ws + OFF_WSF2; float* bns2 = ws + OFF_BNS2; float* bnb2 = ws + OFF_BNB2; float* w2i = ws + OFF_W2I;
    float* wsf3 = ws + OFF_WSF3; float* bns3 = ws + OFF_BNS3; float* bnb3 = ws + OFF_BNB3; float* w3i = ws + OFF_W3I;
    float* wsf4 = ws + OFF_WSF4; float* bns4 = ws + OFF_BNS4; float* bnb4 = ws + OFF_BNB4; float* w4i = ws + OFF_W4I;
    float* wsfd = ws + OFF_WSFD; float* wdi = ws + OFF_WDI;
    float* logits = ws + OFF_LOG;
    float* actA = ws + ACT_A_OFF;   // act2 / act4
    float* actB = ws + ACT_B_OFF;   // act1 / act3

    PrepAll pa;
    pa.umax = umax;
    const float* ww[6] = {w[0], w[1], w[2], w[3], w[4], wd};
    float* wsfp[6] = {wsf0, wsf1, wsf2, wsf3, wsf4, wsfd};
    float* wip[6]  = {w0i, w1i, w2i, w3i, w4i, wdi};
    float* bnsp[6] = {bns0, bns1, bns2, bns3, bns4, nullptr};
    float* bnbp[6] = {bnb0, bnb1, bnb2, bnb3, bnb4, nullptr};
    int Ks[6] = {27, 32, 36, 288, 288, 2048};
    for (int i = 0; i < 6; ++i) {
        pa.e[i].w = ww[i];
        pa.e[i].g = (i < 5) ? g[i] : nullptr;
        pa.e[i].bb = (i < 5) ? bb[i] : nullptr;
        pa.e[i].m = (i < 5) ? m[i] : nullptr;
        pa.e[i].v = (i < 5) ? v[i] : nullptr;
        pa.e[i].wsf = wsfp[i];
        pa.e[i].wint = wip[i];
        pa.e[i].bns = bnsp[i];
        pa.e[i].bnb = bnbp[i];
        pa.e[i].K = Ks[i];
        pa.e[i].has_bn = (i < 5) ? 1 : 0;
    }

    hipLaunchKernelGGL(k_prep_all, dim3(143), dim3(256), 0, stream, pa);
    hipLaunchKernelGGL(k_absmax, dim3(1024), dim3(256), 0, stream,
                       (const float4*)x, 1024 * 3 * 32 * 32 / 4, umax + 0);
    hipLaunchKernelGGL(k_conv0max, dim3(1024), dim3(256), 0, stream,
                       x, w0i, wsf0, bia[0], bns0, bnb0, umax, umax + 1);
    hipLaunchKernelGGL(k_conv01, dim3(1024), dim3(256), 0, stream,
                       x, w0i, wsf0, bia[0], bns0, bnb0,
                       w1i, wsf1, bia[1], bns1, bnb1, umax, umax + 2, actB);
    hipLaunchKernelGGL(k_conv2, dim3(1024), dim3(256), 0, stream,
                       actB, w2i, wsf2, bia[2], bns2, bnb2, umax, umax + 3, actA);
    hipLaunchKernelGGL((k_conv34<16, 2>), dim3(1024), dim3(256), 0, stream,
                       actA, w3i, wsf3, bia[3], bns3, bnb3, umax, 3, umax + 4, actB);
    hipLaunchKernelGGL((k_conv34<8, 1>),  dim3(1024), dim3(256), 0, stream,
                       actB, w4i, wsf4, bia[4], bns4, bnb4, umax, 4, umax + 5, actA);
    hipLaunchKernelGGL(k_fc, dim3(1024), dim3(256), 0, stream, actA, wdi, wsfd, bd, umax, logits);
    hipLaunchKernelGGL(k_softmax, dim3(10), dim3(256), 0, stream, logits, out);
}

// Round 3
// 382.013 us; speedup vs baseline: 1.5990x; 1.2257x over previous
//
#include <hip/hip_runtime.h>

#define DI __device__ __forceinline__

// ---------------- ws layout (float offsets), all 4-float aligned ----------------
// umax[8] (uint32) at 0:
//   [0]=|x| [1]=|act0| [2]=|act1| [3]=|act2| [4]=|act3| [5]=|act4|
constexpr int OFF_WSF0 = 8;
constexpr int OFF_BNS0 = 40;
constexpr int OFF_BNB0 = 72;
constexpr int OFF_W0I  = 104;    // 32*27 = 864
constexpr int OFF_WSF1 = 968;
constexpr int OFF_BNS1 = 972;
constexpr int OFF_BNB1 = 976;
constexpr int OFF_W1I  = 980;    // 4*32 = 128
constexpr int OFF_WSF2 = 1108;
constexpr int OFF_BNS2 = 1140;
constexpr int OFF_BNB2 = 1172;
constexpr int OFF_W2I  = 1204;   // 32*36 = 1152
constexpr int OFF_WSF3 = 2356;
constexpr int OFF_BNS3 = 2388;
constexpr int OFF_BNB3 = 2420;
constexpr int OFF_W3I  = 2452;   // 32*288 = 9216
constexpr int OFF_WSF4 = 11668;
constexpr int OFF_BNS4 = 11700;
constexpr int OFF_BNB4 = 11732;
constexpr int OFF_W4I  = 11764;  // 9216
constexpr int OFF_WSFD = 20980;  // 10
constexpr int OFF_WDI  = 20992;  // 10*2048 = 20480
constexpr int OFF_LOG  = 41472;  // 1024*10
constexpr int OFF_ACT  = 51712;
constexpr long ACT_A_OFF = OFF_ACT;              // act2/act4 (8,388,608 floats)
constexpr long ACT_B_OFF = OFF_ACT + 8388608L;   // act1/act3 (4,194,304 floats)

// ---------------- helpers ----------------
DI float quantv(float x, float sf) {
    float q = rintf(x / sf);
    return fminf(fmaxf(q, -127.0f), 127.0f);
}
DI float get_sf(const unsigned* umax, int slot) {
    return fmaxf(__uint_as_float(umax[slot]) / 127.0f, 1e-8f);
}
DI void wave_max_atomic(float v, unsigned* dst) {
    #pragma unroll
    for (int o = 32; o; o >>= 1) v = fmaxf(v, __shfl_down(v, o, 64));
    if ((threadIdx.x & 63) == 0) atomicMax(dst, __float_as_uint(v));
}

// ---------------- prep: weight quant + BN fold, all layers in one launch ----------------
struct PrepEntry {
    const float *w, *g, *bb, *m, *v;
    float *wsf, *wint, *bns, *bnb;
    int K; int has_bn;
};
struct PrepAll { PrepEntry e[6]; unsigned* umax; };

__global__ __launch_bounds__(256) void k_prep_all(PrepAll pa) {
    int blk = blockIdx.x;
    if (blk == 142) { if (threadIdx.x < 8) pa.umax[threadIdx.x] = 0u; return; }
    int layer, oc;
    if      (blk < 32)  { layer = 0; oc = blk; }
    else if (blk < 36)  { layer = 1; oc = blk - 32; }
    else if (blk < 68)  { layer = 2; oc = blk - 36; }
    else if (blk < 100) { layer = 3; oc = blk - 68; }
    else if (blk < 132) { layer = 4; oc = blk - 100; }
    else                { layer = 5; oc = blk - 132; }
    PrepEntry a = pa.e[layer];
    const float* wr = a.w + (long)oc * a.K;
    float mx = 0.f;
    for (int i = threadIdx.x; i < a.K; i += 256) mx = fmaxf(mx, fabsf(wr[i]));
    __shared__ float red[4];
    __shared__ float s_sf;
    #pragma unroll
    for (int o = 32; o; o >>= 1) mx = fmaxf(mx, __shfl_down(mx, o, 64));
    if ((threadIdx.x & 63) == 0) red[threadIdx.x >> 6] = mx;
    __syncthreads();
    if (threadIdx.x == 0) {
        float t = fmaxf(fmaxf(red[0], red[1]), fmaxf(red[2], red[3]));
        t = fmaxf(t / 127.0f, 1e-8f);
        a.wsf[oc] = t; s_sf = t;
        if (a.has_bn) {
            float inv = a.g[oc] / sqrtf(a.v[oc] + 1e-5f);
            a.bns[oc] = inv;
            a.bnb[oc] = a.bb[oc] - a.m[oc] * inv;
        }
    }
    __syncthreads();
    float sf = s_sf;
    for (int i = threadIdx.x; i < a.K; i += 256) a.wint[(long)oc * a.K + i] = rintf(wr[i] / sf);
}

__global__ __launch_bounds__(256) void k_absmax(const float4* __restrict__ x, int n4, unsigned* dst) {
    float m = 0.f;
    for (int i = blockIdx.x * blockDim.x + threadIdx.x; i < n4; i += gridDim.x * blockDim.x) {
        float4 t = x[i];
        m = fmaxf(m, fmaxf(fmaxf(fabsf(t.x), fabsf(t.y)), fmaxf(fabsf(t.z), fabsf(t.w))));
    }
    wave_max_atomic(m, dst);
}

// ---------------- conv0 common machinery ----------------
DI void conv0_stage(const float* xb, float sfx, float* tile) {
    for (int i = threadIdx.x; i < 3 * 1156; i += 256) {
        int ci = i / 1156, r = i % 1156;
        int yy = r / 34, xx = r % 34;
        int iy = yy - 1, ix = xx - 1;
        float val = 0.f;
        if ((unsigned)iy < 32u && (unsigned)ix < 32u)
            val = quantv(xb[ci * 1024 + iy * 32 + ix], sfx);
        tile[i] = val;
    }
}
DI void conv0_inregs(const float* tile, int h, int w0, float in[3][3][6]) {
    #pragma unroll
    for (int ci = 0; ci < 3; ++ci)
        #pragma unroll
        for (int r = 0; r < 3; ++r)
            #pragma unroll
            for (int c = 0; c < 6; ++c)
                in[ci][r][c] = tile[ci * 1156 + (h + r) * 34 + (w0 + c)];
}
DI void conv0_oc(const float in[3][3][6], const float* w0s, int oc, float acc[4]) {
    acc[0] = acc[1] = acc[2] = acc[3] = 0.f;
    #pragma unroll
    for (int ci = 0; ci < 3; ++ci)
        #pragma unroll
        for (int ky = 0; ky < 3; ++ky)
            #pragma unroll
            for (int kx = 0; kx < 3; ++kx) {
                float wv = w0s[oc * 27 + ci * 9 + ky * 3 + kx];
                #pragma unroll
                for (int dx = 0; dx < 4; ++dx)
                    acc[dx] = fmaf(in[ci][ky][kx + dx], wv, acc[dx]);
            }
}

// pass 1: conv0+BN, global max of act0 only — no write
__global__ __launch_bounds__(256) void k_conv0max(
    const float* __restrict__ x, const float* __restrict__ w0i,
    const float* __restrict__ wsf0, const float* __restrict__ bias0,
    const float* __restrict__ bns0, const float* __restrict__ bnb0,
    const unsigned* __restrict__ umax, unsigned* __restrict__ mout) {
    int b = blockIdx.x;
    __shared__ float tile[3 * 1156];
    __shared__ float w0s[864];
    __shared__ float A0s[32], C0s[32];
    float sfx = get_sf(umax, 0);
    if (threadIdx.x < 32) {
        int oc = threadIdx.x;
        float bsf = wsf0[oc] * sfx;
        float bint = rintf(bias0[oc] / bsf);
        float a = bsf * bns0[oc];
        A0s[oc] = a;
        C0s[oc] = fmaf(bint, a, bnb0[oc]);
    }
    for (int i = threadIdx.x; i < 864; i += 256) w0s[i] = w0i[i];
    conv0_stage(x + (long)b * 3072, sfx, tile);
    __syncthreads();
    int t = threadIdx.x;
    int h = t >> 3, w0 = (t & 7) * 4;
    float in[3][3][6];
    conv0_inregs(tile, h, w0, in);
    float lmax = 0.f;
    for (int oc = 0; oc < 32; ++oc) {
        float acc[4];
        conv0_oc(in, w0s, oc, acc);
        float A = A0s[oc], C = C0s[oc];
        #pragma unroll
        for (int dx = 0; dx < 4; ++dx)
            lmax = fmaxf(lmax, fabsf(fmaf(acc[dx], A, C)));
    }
    wave_max_atomic(lmax, mout);
}

// pass 2: recompute conv0 (identical) + quantize act0 on the fly + fused 1x1 conv1+BN
__global__ __launch_bounds__(256) void k_conv01(
    const float* __restrict__ x, const float* __restrict__ w0i,
    const float* __restrict__ wsf0, const float* __restrict__ bias0,
    const float* __restrict__ bns0, const float* __restrict__ bnb0,
    const float* __restrict__ w1i,
    const float* __restrict__ wsf1, const float* __restrict__ bias1,
    const float* __restrict__ bns1, const float* __restrict__ bnb1,
    const unsigned* __restrict__ umax, unsigned* __restrict__ mout,
    float* __restrict__ out) {
    int b = blockIdx.x;
    __shared__ float tile[3 * 1156];
    __shared__ float w0s[864];
    __shared__ float w1s[128];
    __shared__ float A0s[32], C0s[32];
    __shared__ float A1s[4], C1s[4];
    float sfx = get_sf(umax, 0);
    float sf1 = get_sf(umax, 1);
    if (threadIdx.x < 32) {
        int oc = threadIdx.x;
        float bsf = wsf0[oc] * sfx;
        float bint = rintf(bias0[oc] / bsf);
        float a = bsf * bns0[oc];
        A0s[oc] = a;
        C0s[oc] = fmaf(bint, a, bnb0[oc]);
    }
    if (threadIdx.x >= 64 && threadIdx.x < 68) {
        int oc = threadIdx.x - 64;
        float bsf = wsf1[oc] * sf1;
        float bint = rintf(bias1[oc] / bsf);
        float a = bsf * bns1[oc];
        A1s[oc] = a;
        C1s[oc] = fmaf(bint, a, bnb1[oc]);
    }
    for (int i = threadIdx.x; i < 864; i += 256) w0s[i] = w0i[i];
    if (threadIdx.x >= 128 && threadIdx.x < 256) w1s[threadIdx.x - 128] = w1i[threadIdx.x - 128];
    conv0_stage(x + (long)b * 3072, sfx, tile);
    __syncthreads();
    int t = threadIdx.x;
    int h = t >> 3, w0 = (t & 7) * 4;
    float in[3][3][6];
    conv0_inregs(tile, h, w0, in);
    float acc1[4][4] = {{0.f}};
    for (int oc = 0; oc < 32; ++oc) {
        float acc[4];
        conv0_oc(in, w0s, oc, acc);
        float A = A0s[oc], C = C0s[oc];
        float wv0 = w1s[oc], wv1 = w1s[32 + oc], wv2 = w1s[64 + oc], wv3 = w1s[96 + oc];
        #pragma unroll
        for (int dx = 0; dx < 4; ++dx) {
            float y = fmaf(acc[dx], A, C);
            float q = quantv(y, sf1);
            acc1[0][dx] = fmaf(q, wv0, acc1[0][dx]);
            acc1[1][dx] = fmaf(q, wv1, acc1[1][dx]);
            acc1[2][dx] = fmaf(q, wv2, acc1[2][dx]);
            acc1[3][dx] = fmaf(q, wv3, acc1[3][dx]);
        }
    }
    float lmax = 0.f;
    float* ob = out + (long)b * 4096;
    #pragma unroll
    for (int o1 = 0; o1 < 4; ++o1) {
        float A = A1s[o1], C = C1s[o1];
        float4 res;
        float* rp = &res.x;
        #pragma unroll
        for (int dx = 0; dx < 4; ++dx) {
            float y = fmaf(acc1[o1][dx], A, C);
            rp[dx] = y;
            lmax = fmaxf(lmax, fabsf(y));
        }
        *(float4*)&ob[o1 * 1024 + h * 32 + w0] = res;
    }
    wave_max_atomic(lmax, mout);
}

// ---------------- conv2 (4->32, 3x3, s2, 32x32 -> 16x16), register-blocked ----------------
// block = 1 image; tid = ocg(2b)<<6 | pxq(6b); thread = 4px x 8oc.
// weights staged oc-last (wlds[k][36]) -> one b128x2 fetches the lane's 8 oc.
__global__ __launch_bounds__(256) void k_conv2b(
    const float* __restrict__ inp, const float* __restrict__ wi,
    const float* __restrict__ wsf, const float* __restrict__ bias,
    const float* __restrict__ bns, const float* __restrict__ bnb,
    const unsigned* __restrict__ umax, unsigned* __restrict__ mout,
    float* __restrict__ out) {
    constexpr int RS = 36, ROWS = 34;
    __shared__ float tile[4 * ROWS * RS];   // 4896 floats
    __shared__ float wlds[36 * 36];
    __shared__ float As[32], Cs[32];
    const int tid = threadIdx.x;
    const int ocg = tid >> 6;        // 0..3, 8 oc each (wave-uniform)
    const int pxq = tid & 63;
    const int h = pxq >> 2, c = pxq & 3;
    float sf = get_sf(umax, 2);
    if (tid < 32) {
        int oc = tid;
        float bsf = wsf[oc] * sf;
        float bint = rintf(bias[oc] / bsf);
        float a = bsf * bns[oc];
        As[oc] = a;
        Cs[oc] = fmaf(bint, a, bnb[oc]);
    }
    for (int i = tid; i < 4 * ROWS * RS; i += 256) tile[i] = 0.f;
    __syncthreads();
    const float* ib = inp + (long)blockIdx.x * 4096;
    for (int i = tid; i < 4096; i += 256) {
        int ci = i >> 10, px = i & 1023;
        int iy = px >> 5, ix = px & 31;
        tile[ci * (ROWS * RS) + (iy + 1) * RS + (ix + 1)] = quantv(ib[i], sf);
    }
    for (int i = tid; i < 1152; i += 256) {
        int oc = i / 36, k = i - oc * 36;
        wlds[k * 36 + oc] = wi[oc * 36 + k];
    }
    __syncthreads();
    float acc[32];
    #pragma unroll
    for (int i = 0; i < 32; ++i) acc[i] = 0.f;
    #pragma unroll
    for (int ci = 0; ci < 4; ++ci) {
        float win[3][12];
        #pragma unroll
        for (int ky = 0; ky < 3; ++ky) {
            const float* rp = tile + ci * (ROWS * RS) + (2 * h + ky) * RS + 8 * c;
            #pragma unroll
            for (int d = 0; d < 3; ++d)
                *(float4*)&win[ky][4 * d] = *(const float4*)&rp[4 * d];
        }
        #pragma unroll
        for (int ky = 0; ky < 3; ++ky)
            #pragma unroll
            for (int kx = 0; kx < 3; ++kx) {
                int j = ky * 3 + kx;
                const float* wp = &wlds[(ci * 9 + j) * 36 + ocg * 8];
                float4 wa = *(const float4*)&wp[0];
                float4 wb = *(const float4*)&wp[4];
                float wvf[8] = {wa.x, wa.y, wa.z, wa.w, wb.x, wb.y, wb.z, wb.w};
                #pragma unroll
                for (int k = 0; k < 8; ++k)
                    #pragma unroll
                    for (int px = 0; px < 4; ++px)
                        acc[k * 4 + px] = fmaf(win[ky][2 * px + kx], wvf[k], acc[k * 4 + px]);
            }
    }
    float lmax = 0.f;
    float* ob = out + (long)blockIdx.x * 8192;
    #pragma unroll
    for (int k = 0; k < 8; ++k) {
        int oc = ocg * 8 + k;
        float A = As[oc], C = Cs[oc];
        float4 r;
        float* rp = &r.x;
        #pragma unroll
        for (int px = 0; px < 4; ++px) {
            float y = fmaf(acc[k * 4 + px], A, C);
            rp[px] = y;
            lmax = fmaxf(lmax, fabsf(y));
        }
        *(float4*)&ob[oc * 256 + h * 16 + c * 4] = r;
    }
    wave_max_atomic(lmax, mout);
}

// ---------------- conv3/conv4 (32->32, 3x3, out 8x8), register-blocked + K-phased ----------------
// block = 2 images; tid = imgl(1b)<<7 | ocg(3b)<<4 | pxq(4b); thread = 4px x 4oc.
// 4 phases of 8 ci. Weights oc-last (wlds[k][36]): one b128 = lane's 4 oc.
template<int HIN, int S>
__global__ __launch_bounds__(256) void k_conv34b(
    const float* __restrict__ inp, const float* __restrict__ wi,
    const float* __restrict__ wsf, const float* __restrict__ bias,
    const float* __restrict__ bns, const float* __restrict__ bnb,
    const unsigned* __restrict__ umax, int slot, unsigned* __restrict__ mout,
    float* __restrict__ out) {
    constexpr int ROWS = HIN + 2;
    constexpr int RS   = (S == 2) ? 20 : 12;   // padded row stride (16B-aligned rows)
    constexpr int TI   = 8 * ROWS * RS;        // per-image per-phase tile floats
    constexpr int PIX  = HIN * HIN;
    constexpr int NELT = 2 * 8 * PIX;
    constexpr int WINW = (S == 2) ? 12 : 8;
    constexpr int ND   = (S == 2) ? 3 : 2;
    __shared__ float tile[2 * TI];
    __shared__ float wlds[72 * 36];
    __shared__ float As[32], Cs[32];
    const int tid  = threadIdx.x;
    const int imgl = tid >> 7;
    const int ocg  = (tid >> 4) & 7;
    const int pxq  = tid & 15;
    const int h = pxq >> 1, c = pxq & 1;
    const float sf = get_sf(umax, slot);
    if (tid < 32) {
        int oc = tid;
        float bsf = wsf[oc] * sf;
        float bint = rintf(bias[oc] / bsf);
        float a = bsf * bns[oc];
        As[oc] = a;
        Cs[oc] = fmaf(bint, a, bnb[oc]);
    }
    for (int i = tid; i < 2 * TI; i += 256) tile[i] = 0.f;
    float acc[16];
    #pragma unroll
    for (int i = 0; i < 16; ++i) acc[i] = 0.f;
    const float* ib = inp + (long)blockIdx.x * 2 * 32 * PIX;
    for (int ph = 0; ph < 4; ++ph) {
        __syncthreads();
        for (int i = tid; i < NELT; i += 256) {
            int im = i / (8 * PIX);
            int r  = i % (8 * PIX);
            int ci = r / PIX;
            int px = r % PIX;
            int iy = px / HIN, ix = px % HIN;
            float q = quantv(ib[(long)(im * 32 + ph * 8 + ci) * PIX + px], sf);
            tile[im * TI + ci * (ROWS * RS) + (iy + 1) * RS + (ix + 1)] = q;
        }
        for (int i = tid; i < 2304; i += 256) {
            int oc = i / 72, k = i - oc * 72;
            wlds[k * 36 + oc] = wi[oc * 288 + ph * 72 + k];
        }
        __syncthreads();
        const float* tb = tile + imgl * TI;
        #pragma unroll 2
        for (int ci = 0; ci < 8; ++ci) {
            float win[3][WINW];
            #pragma unroll
            for (int ky = 0; ky < 3; ++ky) {
                const float* rp = tb + ci * (ROWS * RS) + (S * h + ky) * RS + S * 4 * c;
                #pragma unroll
                for (int d = 0; d < ND; ++d)
                    *(float4*)&win[ky][4 * d] = *(const float4*)&rp[4 * d];
            }
            #pragma unroll
            for (int ky = 0; ky < 3; ++ky)
                #pragma unroll
                for (int kx = 0; kx < 3; ++kx) {
                    int j = ky * 3 + kx;
                    float4 wv = *(const float4*)&wlds[(ci * 9 + j) * 36 + ocg * 4];
                    float wvf[4] = {wv.x, wv.y, wv.z, wv.w};
                    #pragma unroll
                    for (int k = 0; k < 4; ++k)
                        #pragma unroll
                        for (int px = 0; px < 4; ++px)
                            acc[k * 4 + px] = fmaf(win[ky][S * px + kx], wvf[k], acc[k * 4 + px]);
                }
        }
    }
    float lmax = 0.f;
    long imgg = (long)blockIdx.x * 2 + imgl;
    #pragma unroll
    for (int k = 0; k < 4; ++k) {
        int oc = ocg * 4 + k;
        float A = As[oc], C = Cs[oc];
        float4 r;
        float* rp = &r.x;
        #pragma unroll
        for (int px = 0; px < 4; ++px) {
            float y = fmaf(acc[k * 4 + px], A, C);
            rp[px] = y;
            lmax = fmaxf(lmax, fabsf(y));
        }
        *(float4*)&out[(imgg * 32 + oc) * 64 + h * 8 + c * 4] = r;
    }
    wave_max_atomic(lmax, mout);
}

// linear 2048->10 per image
__global__ __launch_bounds__(256) void k_fc(
    const float* __restrict__ act, const float* __restrict__ wdi,
    const float* __restrict__ wsfd, const float* __restrict__ bd,
    const unsigned* __restrict__ umax, float* __restrict__ logits) {
    int b = blockIdx.x;
    float sf = get_sf(umax, 5);
    const float* ab = act + (long)b * 2048;
    float acc[10] = {0.f, 0.f, 0.f, 0.f, 0.f, 0.f, 0.f, 0.f, 0.f, 0.f};
    #pragma unroll
    for (int k = 0; k < 8; ++k) {
        int j = threadIdx.x + 256 * k;
        float q = quantv(ab[j], sf);
        #pragma unroll
        for (int c = 0; c < 10; ++c) acc[c] = fmaf(q, wdi[c * 2048 + j], acc[c]);
    }
    #pragma unroll
    for (int c = 0; c < 10; ++c)
        #pragma unroll
        for (int o = 32; o; o >>= 1) acc[c] += __shfl_down(acc[c], o, 64);
    __shared__ float red[4][10];
    int wid = threadIdx.x >> 6;
    if ((threadIdx.x & 63) == 0)
        #pragma unroll
        for (int c = 0; c < 10; ++c) red[wid][c] = acc[c];
    __syncthreads();
    if (threadIdx.x < 10) {
        int c = threadIdx.x;
        float s = red[0][c] + red[1][c] + red[2][c] + red[3][c];
        float bsf = wsfd[c] * sf;
        float bint = rintf(bd[c] / bsf);
        logits[b * 10 + c] = (s + bint) * bsf;
    }
}

// softmax over batch axis (dim 0). one block per class column
__global__ __launch_bounds__(256) void k_softmax(const float* __restrict__ logits, float* __restrict__ out) {
    int c = blockIdx.x;
    float v[4];
    #pragma unroll
    for (int k = 0; k < 4; ++k) v[k] = logits[(threadIdx.x + 256 * k) * 10 + c];
    float mx = fmaxf(fmaxf(v[0], v[1]), fmaxf(v[2], v[3]));
    __shared__ float redm[4];
    __shared__ float reds[4];
    #pragma unroll
    for (int o = 32; o; o >>= 1) mx = fmaxf(mx, __shfl_down(mx, o, 64));
    if ((threadIdx.x & 63) == 0) redm[threadIdx.x >> 6] = mx;
    __syncthreads();
    mx = fmaxf(fmaxf(redm[0], redm[1]), fmaxf(redm[2], redm[3]));
    float e[4], s = 0.f;
    #pragma unroll
    for (int k = 0; k < 4; ++k) { e[k] = expf(v[k] - mx); s += e[k]; }
    #pragma unroll
    for (int o = 32; o; o >>= 1) s += __shfl_down(s, o, 64);
    if ((threadIdx.x & 63) == 0) reds[threadIdx.x >> 6] = s;
    __syncthreads();
    s = reds[0] + reds[1] + reds[2] + reds[3];
    #pragma unroll
    for (int k = 0; k < 4; ++k) out[(threadIdx.x + 256 * k) * 10 + c] = e[k] / s;
}

extern "C" void kernel_launch(void* const* d_in, const int* in_sizes, int n_in,
                              void* d_out, int out_size, void* d_ws, size_t ws_size,
                              hipStream_t stream) {
    (void)in_sizes; (void)n_in; (void)out_size; (void)ws_size;
    const float* x = (const float*)d_in[0];
    const float *w[5], *bia[5], *g[5], *bb[5], *m[5], *v[5];
    for (int i = 0; i < 5; ++i) {
        w[i]   = (const float*)d_in[1 + 6 * i + 0];
        bia[i] = (const float*)d_in[1 + 6 * i + 1];
        g[i]   = (const float*)d_in[1 + 6 * i + 2];
        bb[i]  = (const float*)d_in[1 + 6 * i + 3];
        m[i]   = (const float*)d_in[1 + 6 * i + 4];
        v[i]   = (const float*)d_in[1 + 6 * i + 5];
    }
    const float* wd = (const float*)d_in[31];
    const float* bd = (const float*)d_in[32];
    float* ws = (float*)d_ws;
    unsigned* umax = (unsigned*)ws;
    float* out = (float*)d_out;

    float* wsf0 = ws + OFF_WSF0; float* bns0 = ws + OFF_BNS0; float* bnb0 = ws + OFF_BNB0; float* w0i = ws + OFF_W0I;
    float* wsf1 = ws + OFF_WSF1; float* bns1 = ws + OFF_BNS1; float* bnb1 = ws + OFF_BNB1; float* w1i = ws + OFF_W1I;
    float* wsf2 = ws + OFF_WSF2; float* bns2 = ws + OFF_BNS2; float* bnb2 = ws + OFF_BNB2; float* w2i = ws + OFF_W2I;
    float* wsf3 = ws + OFF_WSF3; float* bns3 = ws + OFF_BNS3; float* bnb3 = ws + OFF_BNB3; float* w3i = ws + OFF_W3I;
    float* wsf4 = ws + OFF_WSF4; float* bns4 = ws + OFF_BNS4; float* bnb4 = ws + OFF_BNB4; float* w4i = ws + OFF_W4I;
    float* wsfd = ws + OFF_WSFD; float* wdi = ws + OFF_WDI;
    float* logits = ws + OFF_LOG;
    float* actA = ws + ACT_A_OFF;   // act2 / act4
    float* actB = ws + ACT_B_OFF;   // act1 / act3

    PrepAll pa;
    pa.umax = umax;
    const float* ww[6] = {w[0], w[1], w[2], w[3], w[4], wd};
    float* wsfp[6] = {wsf0, wsf1, wsf2, wsf3, wsf4, wsfd};
    float* wip[6]  = {w0i, w1i, w2i, w3i, w4i, wdi};
    float* bnsp[6] = {bns0, bns1, bns2, bns3, bns4, nullptr};
    float* bnbp[6] = {bnb0, bnb1, bnb2, bnb3, bnb4, nullptr};
    int Ks[6] = {27, 32, 36, 288, 288, 2048};
    for (int i = 0; i < 6; ++i) {
        pa.e[i].w = ww[i];
        pa.e[i].g = (i < 5) ? g[i] : nullptr;
        pa.e[i].bb = (i < 5) ? bb[i] : nullptr;
        pa.e[i].m = (i < 5) ? m[i] : nullptr;
        pa.e[i].v = (i < 5) ? v[i] : nullptr;
        pa.e[i].wsf = wsfp[i];
        pa.e[i].wint = wip[i];
        pa.e[i].bns = bnsp[i];
        pa.e[i].bnb = bnbp[i];
        pa.e[i].K = Ks[i];
        pa.e[i].has_bn = (i < 5) ? 1 : 0;
    }

    hipLaunchKernelGGL(k_prep_all, dim3(143), dim3(256), 0, stream, pa);
    hipLaunchKernelGGL(k_absmax, dim3(1024), dim3(256), 0, stream,
                       (const float4*)x, 1024 * 3 * 32 * 32 / 4, umax + 0);
    hipLaunchKernelGGL(k_conv0max, dim3(1024), dim3(256), 0, stream,
                       x, w0i, wsf0, bia[0], bns0, bnb0, umax, umax + 1);
    hipLaunchKernelGGL(k_conv01, dim3(1024), dim3(256), 0, stream,
                       x, w0i, wsf0, bia[0], bns0, bnb0,
                       w1i, wsf1, bia[1], bns1, bnb1, umax, umax + 2, actB);
    hipLaunchKernelGGL(k_conv2b, dim3(1024), dim3(256), 0, stream,
                       actB, w2i, wsf2, bia[2], bns2, bnb2, umax, umax + 3, actA);
    hipLaunchKernelGGL((k_conv34b<16, 2>), dim3(512), dim3(256), 0, stream,
                       actA, w3i, wsf3, bia[3], bns3, bnb3, umax, 3, umax + 4, actB);
    hipLaunchKernelGGL((k_conv34b<8, 1>),  dim3(512), dim3(256), 0, stream,
                       actB, w4i, wsf4, bia[4], bns4, bnb4, umax, 4, umax + 5, actA);
    hipLaunchKernelGGL(k_fc, dim3(1024), dim3(256), 0, stream, actA, wdi, wsfd, bd, umax, logits);
    hipLaunchKernelGGL(k_softmax, dim3(10), dim3(256), 0, stream, logits, out);
}